// Round 1
// baseline (413.697 us; speedup 1.0000x reference)
//
#include <hip/hip_runtime.h>
#include <math.h>

#define BB 32
#define CC 256
#define HH 64
#define WW 64
#define HWSZ (HH * WW)   // 4096

// ---------------------------------------------------------------------------
// Kernel 1: one pass over x.
//  - chan_sum[b][c]  += sum over this block's 256 spatial positions (atomic)
//  - pool_max[b][hw]  = max over all 256 channels   (owned per thread)
//  - pool_avg[b][hw]  = mean over all 256 channels  (owned per thread)
// Grid: 32 batches * 16 chunks = 512 blocks, 256 threads.
// Each thread owns one spatial position; loop over channels is coalesced
// (64 lanes * 4B = 256B segments per wave per channel).
// ---------------------------------------------------------------------------
__global__ __launch_bounds__(256) void stats_kernel(
    const float* __restrict__ x, float* __restrict__ chan_sum,
    float* __restrict__ pool_max, float* __restrict__ pool_avg) {
  const int b = blockIdx.x >> 4;
  const int pos = ((blockIdx.x & 15) << 8) + threadIdx.x;
  const float* xp = x + (size_t)b * CC * HWSZ + pos;

  float mx = -3.4e38f;
  float sm = 0.0f;

#pragma unroll 4
  for (int c = 0; c < CC; ++c) {
    float v = xp[(size_t)c * HWSZ];
    mx = fmaxf(mx, v);
    sm += v;
    // wave(64)-reduce v, lane 0 accumulates into chan_sum[b][c]
    float s = v;
#pragma unroll
    for (int off = 32; off > 0; off >>= 1) s += __shfl_xor(s, off, 64);
    if ((threadIdx.x & 63) == 0) atomicAdd(&chan_sum[b * CC + c], s);
  }

  pool_max[b * HWSZ + pos] = mx;
  pool_avg[b * HWSZ + pos] = sm * (1.0f / CC);
}

// ---------------------------------------------------------------------------
// Kernel 2: ECA — conv1d(k=5, pad=2, zero) over channel means, sigmoid.
// Grid: 32 blocks (one per batch), 256 threads (one per channel).
// ---------------------------------------------------------------------------
__global__ __launch_bounds__(256) void eca_kernel(
    const float* __restrict__ chan_sum, const float* __restrict__ w5,
    float* __restrict__ ch_w) {
  __shared__ float m[CC];
  const int b = blockIdx.x;
  const int c = threadIdx.x;
  m[c] = chan_sum[b * CC + c] * (1.0f / HWSZ);
  __syncthreads();

  float acc = 0.0f;
#pragma unroll
  for (int k = 0; k < 5; ++k) {
    int cc = c + k - 2;
    float v = (cc >= 0 && cc < CC) ? m[cc] : 0.0f;
    acc = fmaf(v, w5[k], acc);
  }
  ch_w[b * CC + c] = 1.0f / (1.0f + __expf(-acc));
}

// ---------------------------------------------------------------------------
// Kernel 3: spatial attention — 7x7 conv (2 in-ch: max,avg), pad 3, + bias,
// sigmoid. One thread per output pixel; pooled maps (1 MiB) are L2-resident.
// Grid: B*HW/256 = 512 blocks.
// ---------------------------------------------------------------------------
__global__ __launch_bounds__(256) void spatial_kernel(
    const float* __restrict__ pool_max, const float* __restrict__ pool_avg,
    const float* __restrict__ w2, const float* __restrict__ bias,
    float* __restrict__ sp) {
  const int idx = blockIdx.x * 256 + threadIdx.x;  // over B*HW
  const int b = idx >> 12;
  const int hw = idx & (HWSZ - 1);
  const int h = hw >> 6;
  const int w = hw & 63;

  float acc = bias[0];
#pragma unroll
  for (int kh = 0; kh < 7; ++kh) {
    const int hh = h + kh - 3;
    if (hh < 0 || hh >= HH) continue;
#pragma unroll
    for (int kw = 0; kw < 7; ++kw) {
      const int ww = w + kw - 3;
      if (ww < 0 || ww >= WW) continue;
      const int off = b * HWSZ + hh * WW + ww;
      acc = fmaf(pool_max[off], w2[kh * 7 + kw], acc);
      acc = fmaf(pool_avg[off], w2[49 + kh * 7 + kw], acc);
    }
  }
  sp[idx] = 1.0f / (1.0f + __expf(-acc));
}

// ---------------------------------------------------------------------------
// Kernel 4: out = x * (ch_w[b,c] + sp[b,hw] + 1).  float4 streaming.
// Grid: 32M / 4 / 256 = 32768 blocks.
// ---------------------------------------------------------------------------
__global__ __launch_bounds__(256) void combine_kernel(
    const float* __restrict__ x, const float* __restrict__ ch_w,
    const float* __restrict__ sp, float* __restrict__ out) {
  const size_t f = (size_t)blockIdx.x * 256 + threadIdx.x;  // float4 index
  const size_t e = f * 4;                                   // element index
  const int b = (int)(e >> 20);          // C*HW = 2^20
  const int c = (int)(e >> 12) & 255;    // HW = 2^12
  const int hw = (int)e & (HWSZ - 1);

  const float4 x4 = ((const float4*)x)[f];
  const float4 s4 = ((const float4*)(sp + ((size_t)b << 12)))[hw >> 2];
  const float cw = ch_w[b * CC + c] + 1.0f;

  float4 o;
  o.x = x4.x * (cw + s4.x);
  o.y = x4.y * (cw + s4.y);
  o.z = x4.z * (cw + s4.z);
  o.w = x4.w * (cw + s4.w);
  ((float4*)out)[f] = o;
}

extern "C" void kernel_launch(void* const* d_in, const int* in_sizes, int n_in,
                              void* d_out, int out_size, void* d_ws, size_t ws_size,
                              hipStream_t stream) {
  const float* x    = (const float*)d_in[0];  // (32,256,64,64)
  const float* w1   = (const float*)d_in[1];  // (1,1,5)
  const float* w2   = (const float*)d_in[2];  // (1,2,7,7)
  const float* bias = (const float*)d_in[3];  // (1,)
  float* out = (float*)d_out;

  float* ws = (float*)d_ws;
  float* chan_sum = ws;                        // 8192 floats
  float* ch_w     = ws + 8192;                 // 8192
  float* pool_max = ws + 16384;                // 131072
  float* pool_avg = ws + 147456;               // 131072
  float* sp       = ws + 278528;               // 131072  (end: 409600 floats)

  // chan_sum accumulated via atomics — must start at zero every call.
  hipMemsetAsync(chan_sum, 0, (size_t)BB * CC * sizeof(float), stream);

  stats_kernel<<<BB * 16, 256, 0, stream>>>(x, chan_sum, pool_max, pool_avg);
  eca_kernel<<<BB, 256, 0, stream>>>(chan_sum, w1, ch_w);
  spatial_kernel<<<(BB * HWSZ) / 256, 256, 0, stream>>>(pool_max, pool_avg, w2, bias, sp);
  combine_kernel<<<(BB * CC * HWSZ) / (4 * 256), 256, 0, stream>>>(x, ch_w, sp, out);
}

// Round 2
// 312.021 us; speedup vs baseline: 1.3259x; 1.3259x over previous
//
#include <hip/hip_runtime.h>
#include <math.h>

#define BB 32
#define CC 256
#define HH 64
#define WW 64
#define HWSZ (HH * WW)   // 4096

// Monotone float-max merge via integer atomics:
//  - val >= 0: int-compare works (any stored negative/init loses)
//  - val <  0: uint-compare is reversed for negatives -> atomicMin
// Init pattern 0xFFFFFFFF loses to every real value on both paths.
__device__ inline void atomicMaxFloat(float* addr, float val) {
  if (val >= 0.0f) atomicMax((int*)addr, __float_as_int(val));
  else             atomicMin((unsigned int*)addr, __float_as_uint(val));
}

// ---------------------------------------------------------------------------
// Kernel 1: one pass over x, channel-split for occupancy.
// Grid: 32 b x 16 cchunk x 4 hwchunk = 2048 blocks, 256 threads.
// Each thread: float4 over 4 hw positions, 16 channels (independent loads).
//  - chan_sum[b][c]   += wave-reduced partial (1 atomic / wave / channel)
//  - pool_max[b][hw]   = atomic monotone max merge across 16 cchunks
//  - pool_sum[b][hw]  += atomicAdd merge across 16 cchunks
// ---------------------------------------------------------------------------
__global__ __launch_bounds__(256) void stats_kernel(
    const float* __restrict__ x, float* __restrict__ chan_sum,
    float* __restrict__ pool_max, float* __restrict__ pool_sum) {
  const int b = blockIdx.x >> 6;
  const int rem = blockIdx.x & 63;
  const int cchunk = rem >> 2;     // 16 chunks of 16 channels
  const int hwchunk = rem & 3;     // 4 chunks of 1024 positions
  const int c0 = cchunk << 4;
  const int hw0 = (hwchunk << 10) + (threadIdx.x << 2);

  const float4* xp = (const float4*)(x + ((size_t)b << 20) + ((size_t)c0 << 12) + hw0);

  float4 mx = make_float4(-3.4e38f, -3.4e38f, -3.4e38f, -3.4e38f);
  float4 sm = make_float4(0.f, 0.f, 0.f, 0.f);

#pragma unroll
  for (int ci = 0; ci < 16; ++ci) {
    const float4 v = xp[ci * (HWSZ / 4)];
    mx.x = fmaxf(mx.x, v.x); mx.y = fmaxf(mx.y, v.y);
    mx.z = fmaxf(mx.z, v.z); mx.w = fmaxf(mx.w, v.w);
    sm.x += v.x; sm.y += v.y; sm.z += v.z; sm.w += v.w;

    // per-channel sum: wave(64) butterfly, lane 0 commits
    float s = (v.x + v.y) + (v.z + v.w);
#pragma unroll
    for (int off = 32; off > 0; off >>= 1) s += __shfl_xor(s, off, 64);
    if ((threadIdx.x & 63) == 0) atomicAdd(&chan_sum[b * CC + c0 + ci], s);
  }

  const int pidx = (b << 12) + hw0;
  atomicMaxFloat(&pool_max[pidx + 0], mx.x);
  atomicMaxFloat(&pool_max[pidx + 1], mx.y);
  atomicMaxFloat(&pool_max[pidx + 2], mx.z);
  atomicMaxFloat(&pool_max[pidx + 3], mx.w);
  atomicAdd(&pool_sum[pidx + 0], sm.x);
  atomicAdd(&pool_sum[pidx + 1], sm.y);
  atomicAdd(&pool_sum[pidx + 2], sm.z);
  atomicAdd(&pool_sum[pidx + 3], sm.w);
}

// ---------------------------------------------------------------------------
// Kernel 2: ECA — conv1d(k=5, pad=2, zero) over channel means, sigmoid.
// ---------------------------------------------------------------------------
__global__ __launch_bounds__(256) void eca_kernel(
    const float* __restrict__ chan_sum, const float* __restrict__ w5,
    float* __restrict__ ch_w) {
  __shared__ float m[CC];
  const int b = blockIdx.x;
  const int c = threadIdx.x;
  m[c] = chan_sum[b * CC + c] * (1.0f / HWSZ);
  __syncthreads();

  float acc = 0.0f;
#pragma unroll
  for (int k = 0; k < 5; ++k) {
    int cc = c + k - 2;
    float v = (cc >= 0 && cc < CC) ? m[cc] : 0.0f;
    acc = fmaf(v, w5[k], acc);
  }
  ch_w[b * CC + c] = 1.0f / (1.0f + __expf(-acc));
}

// ---------------------------------------------------------------------------
// Kernel 3: spatial attention — 7x7 conv (max, sum/256), pad 3, +bias, sigmoid.
// Pooled maps are 1 MiB -> L2-resident scalar loads are fine.
// ---------------------------------------------------------------------------
__global__ __launch_bounds__(256) void spatial_kernel(
    const float* __restrict__ pool_max, const float* __restrict__ pool_sum,
    const float* __restrict__ w2, const float* __restrict__ bias,
    float* __restrict__ sp) {
  const int idx = blockIdx.x * 256 + threadIdx.x;  // over B*HW
  const int b = idx >> 12;
  const int hw = idx & (HWSZ - 1);
  const int h = hw >> 6;
  const int w = hw & 63;

  float acc = bias[0];
#pragma unroll
  for (int kh = 0; kh < 7; ++kh) {
    const int hh = h + kh - 3;
    if (hh < 0 || hh >= HH) continue;
#pragma unroll
    for (int kw = 0; kw < 7; ++kw) {
      const int ww = w + kw - 3;
      if (ww < 0 || ww >= WW) continue;
      const int off = b * HWSZ + hh * WW + ww;
      acc = fmaf(pool_max[off], w2[kh * 7 + kw], acc);
      acc = fmaf(pool_sum[off], w2[49 + kh * 7 + kw] * (1.0f / CC), acc);
    }
  }
  sp[idx] = 1.0f / (1.0f + __expf(-acc));
}

// ---------------------------------------------------------------------------
// Kernel 4: out = x * (ch_w[b,c] + sp[b,hw] + 1).  float4 streaming.
// ---------------------------------------------------------------------------
__global__ __launch_bounds__(256) void combine_kernel(
    const float* __restrict__ x, const float* __restrict__ ch_w,
    const float* __restrict__ sp, float* __restrict__ out) {
  const size_t f = (size_t)blockIdx.x * 256 + threadIdx.x;  // float4 index
  const size_t e = f * 4;                                   // element index
  const int b = (int)(e >> 20);          // C*HW = 2^20
  const int c = (int)(e >> 12) & 255;    // HW = 2^12
  const int hw = (int)e & (HWSZ - 1);

  const float4 x4 = ((const float4*)x)[f];
  const float4 s4 = ((const float4*)(sp + ((size_t)b << 12)))[hw >> 2];
  const float cw = ch_w[b * CC + c] + 1.0f;

  float4 o;
  o.x = x4.x * (cw + s4.x);
  o.y = x4.y * (cw + s4.y);
  o.z = x4.z * (cw + s4.z);
  o.w = x4.w * (cw + s4.w);
  ((float4*)out)[f] = o;
}

extern "C" void kernel_launch(void* const* d_in, const int* in_sizes, int n_in,
                              void* d_out, int out_size, void* d_ws, size_t ws_size,
                              hipStream_t stream) {
  const float* x    = (const float*)d_in[0];  // (32,256,64,64)
  const float* w1   = (const float*)d_in[1];  // (1,1,5)
  const float* w2   = (const float*)d_in[2];  // (1,2,7,7)
  const float* bias = (const float*)d_in[3];  // (1,)
  float* out = (float*)d_out;

  float* ws = (float*)d_ws;
  float* chan_sum = ws;                        // 8192 floats   (zero)
  float* ch_w     = ws + 8192;                 // 8192
  float* pool_sum = ws + 16384;                // 131072 floats (zero)
  float* pool_max = ws + 147456;               // 131072 floats (0xFF fill)
  float* sp       = ws + 278528;               // 131072 floats

  // zero chan_sum..pool_sum; 0xFF-fill pool_max (loses to all reals in merge)
  hipMemsetAsync(ws, 0, (size_t)147456 * sizeof(float), stream);
  hipMemsetAsync(pool_max, 0xFF, (size_t)131072 * sizeof(float), stream);

  stats_kernel<<<BB * 64, 256, 0, stream>>>(x, chan_sum, pool_max, pool_sum);
  eca_kernel<<<BB, 256, 0, stream>>>(chan_sum, w1, ch_w);
  spatial_kernel<<<(BB * HWSZ) / 256, 256, 0, stream>>>(pool_max, pool_sum, w2, bias, sp);
  combine_kernel<<<(BB * CC * HWSZ) / (4 * 256), 256, 0, stream>>>(x, ch_w, sp, out);
}

// Round 3
// 296.494 us; speedup vs baseline: 1.3953x; 1.0524x over previous
//
#include <hip/hip_runtime.h>
#include <math.h>

#define BB 32
#define CC 256
#define HH 64
#define WW 64
#define HWSZ (HH * WW)   // 4096

// Monotone float-max merge via integer atomics:
//  - val >= 0: int-compare works (any stored negative/init loses)
//  - val <  0: uint-compare is reversed for negatives -> atomicMin
// Init pattern 0xFFFFFFFF loses to every real value on both paths.
__device__ inline void atomicMaxFloat(float* addr, float val) {
  if (val >= 0.0f) atomicMax((int*)addr, __float_as_int(val));
  else             atomicMin((unsigned int*)addr, __float_as_uint(val));
}

// ---------------------------------------------------------------------------
// Kernel 1: one pass over x, channel-split for occupancy.
// Grid: 32 b x 16 cchunk x 4 hwchunk = 2048 blocks, 256 threads.
// Each thread: float4 over 4 hw positions, 16 channels.
// Load loop has NO cross-lane ops (16 independent loads pipeline freely);
// per-channel partials held in registers, butterfly-reduced once at the end.
// ---------------------------------------------------------------------------
__global__ __launch_bounds__(256) void stats_kernel(
    const float* __restrict__ x, float* __restrict__ chan_sum,
    float* __restrict__ pool_max, float* __restrict__ pool_sum) {
  const int b = blockIdx.x >> 6;
  const int rem = blockIdx.x & 63;
  const int cchunk = rem >> 2;     // 16 chunks of 16 channels
  const int hwchunk = rem & 3;     // 4 chunks of 1024 positions
  const int c0 = cchunk << 4;
  const int hw0 = (hwchunk << 10) + (threadIdx.x << 2);

  const float4* xp = (const float4*)(x + ((size_t)b << 20) + ((size_t)c0 << 12) + hw0);

  float4 mx = make_float4(-3.4e38f, -3.4e38f, -3.4e38f, -3.4e38f);
  float4 sm = make_float4(0.f, 0.f, 0.f, 0.f);
  float s[16];

#pragma unroll
  for (int ci = 0; ci < 16; ++ci) {
    const float4 v = xp[ci * (HWSZ / 4)];
    mx.x = fmaxf(mx.x, v.x); mx.y = fmaxf(mx.y, v.y);
    mx.z = fmaxf(mx.z, v.z); mx.w = fmaxf(mx.w, v.w);
    sm.x += v.x; sm.y += v.y; sm.z += v.z; sm.w += v.w;
    s[ci] = (v.x + v.y) + (v.z + v.w);   // per-thread partial, no cross-lane
  }

  // Spatial pool merges (4-deep per location across hw-owning blocks is 1:1;
  // 16 cchunk blocks merge atomically per location).
  const int pidx = (b << 12) + hw0;
  atomicMaxFloat(&pool_max[pidx + 0], mx.x);
  atomicMaxFloat(&pool_max[pidx + 1], mx.y);
  atomicMaxFloat(&pool_max[pidx + 2], mx.z);
  atomicMaxFloat(&pool_max[pidx + 3], mx.w);
  atomicAdd(&pool_sum[pidx + 0], sm.x);
  atomicAdd(&pool_sum[pidx + 1], sm.y);
  atomicAdd(&pool_sum[pidx + 2], sm.z);
  atomicAdd(&pool_sum[pidx + 3], sm.w);

  // Per-channel sums: 16 independent 6-deep butterfly chains, then 1 atomic
  // per wave per channel.
#pragma unroll
  for (int ci = 0; ci < 16; ++ci) {
    float v = s[ci];
#pragma unroll
    for (int off = 32; off > 0; off >>= 1) v += __shfl_xor(v, off, 64);
    if ((threadIdx.x & 63) == 0) atomicAdd(&chan_sum[b * CC + c0 + ci], v);
  }
}

// ---------------------------------------------------------------------------
// Kernel 2: ECA — conv1d(k=5, pad=2, zero) over channel means, sigmoid.
// ---------------------------------------------------------------------------
__global__ __launch_bounds__(256) void eca_kernel(
    const float* __restrict__ chan_sum, const float* __restrict__ w5,
    float* __restrict__ ch_w) {
  __shared__ float m[CC];
  const int b = blockIdx.x;
  const int c = threadIdx.x;
  m[c] = chan_sum[b * CC + c] * (1.0f / HWSZ);
  __syncthreads();

  float acc = 0.0f;
#pragma unroll
  for (int k = 0; k < 5; ++k) {
    int cc = c + k - 2;
    float v = (cc >= 0 && cc < CC) ? m[cc] : 0.0f;
    acc = fmaf(v, w5[k], acc);
  }
  ch_w[b * CC + c] = 1.0f / (1.0f + __expf(-acc));
}

// ---------------------------------------------------------------------------
// Kernel 3: spatial attention — 7x7 conv (max, sum/256), pad 3, +bias, sigmoid.
// ---------------------------------------------------------------------------
__global__ __launch_bounds__(256) void spatial_kernel(
    const float* __restrict__ pool_max, const float* __restrict__ pool_sum,
    const float* __restrict__ w2, const float* __restrict__ bias,
    float* __restrict__ sp) {
  const int idx = blockIdx.x * 256 + threadIdx.x;  // over B*HW
  const int b = idx >> 12;
  const int hw = idx & (HWSZ - 1);
  const int h = hw >> 6;
  const int w = hw & 63;

  float acc = bias[0];
#pragma unroll
  for (int kh = 0; kh < 7; ++kh) {
    const int hh = h + kh - 3;
    if (hh < 0 || hh >= HH) continue;
#pragma unroll
    for (int kw = 0; kw < 7; ++kw) {
      const int ww = w + kw - 3;
      if (ww < 0 || ww >= WW) continue;
      const int off = b * HWSZ + hh * WW + ww;
      acc = fmaf(pool_max[off], w2[kh * 7 + kw], acc);
      acc = fmaf(pool_sum[off], w2[49 + kh * 7 + kw] * (1.0f / CC), acc);
    }
  }
  sp[idx] = 1.0f / (1.0f + __expf(-acc));
}

// ---------------------------------------------------------------------------
// Kernel 4: out = x * (ch_w[b,c] + sp[b,hw] + 1).  float4 streaming.
// ---------------------------------------------------------------------------
__global__ __launch_bounds__(256) void combine_kernel(
    const float* __restrict__ x, const float* __restrict__ ch_w,
    const float* __restrict__ sp, float* __restrict__ out) {
  const size_t f = (size_t)blockIdx.x * 256 + threadIdx.x;  // float4 index
  const size_t e = f * 4;                                   // element index
  const int b = (int)(e >> 20);          // C*HW = 2^20
  const int c = (int)(e >> 12) & 255;    // HW = 2^12
  const int hw = (int)e & (HWSZ - 1);

  const float4 x4 = ((const float4*)x)[f];
  const float4 s4 = ((const float4*)(sp + ((size_t)b << 12)))[hw >> 2];
  const float cw = ch_w[b * CC + c] + 1.0f;

  float4 o;
  o.x = x4.x * (cw + s4.x);
  o.y = x4.y * (cw + s4.y);
  o.z = x4.z * (cw + s4.z);
  o.w = x4.w * (cw + s4.w);
  ((float4*)out)[f] = o;
}

extern "C" void kernel_launch(void* const* d_in, const int* in_sizes, int n_in,
                              void* d_out, int out_size, void* d_ws, size_t ws_size,
                              hipStream_t stream) {
  const float* x    = (const float*)d_in[0];  // (32,256,64,64)
  const float* w1   = (const float*)d_in[1];  // (1,1,5)
  const float* w2   = (const float*)d_in[2];  // (1,2,7,7)
  const float* bias = (const float*)d_in[3];  // (1,)
  float* out = (float*)d_out;

  float* ws = (float*)d_ws;
  float* chan_sum = ws;                        // 8192 floats   (zero)
  float* ch_w     = ws + 8192;                 // 8192
  float* pool_sum = ws + 16384;                // 131072 floats (zero)
  float* pool_max = ws + 147456;               // 131072 floats (0xFF fill)
  float* sp       = ws + 278528;               // 131072 floats

  // zero chan_sum..pool_sum; 0xFF-fill pool_max (loses to all reals in merge)
  hipMemsetAsync(ws, 0, (size_t)147456 * sizeof(float), stream);
  hipMemsetAsync(pool_max, 0xFF, (size_t)131072 * sizeof(float), stream);

  stats_kernel<<<BB * 64, 256, 0, stream>>>(x, chan_sum, pool_max, pool_sum);
  eca_kernel<<<BB, 256, 0, stream>>>(chan_sum, w1, ch_w);
  spatial_kernel<<<(BB * HWSZ) / 256, 256, 0, stream>>>(pool_max, pool_sum, w2, bias, sp);
  combine_kernel<<<(BB * CC * HWSZ) / (4 * 256), 256, 0, stream>>>(x, ch_w, sp, out);
}